// Round 9
// baseline (477.064 us; speedup 1.0000x reference)
//
#include <hip/hip_runtime.h>
#include <hip/hip_bf16.h>
#include <math.h>

typedef __bf16 bf16_t;
typedef __bf16 bf16x8 __attribute__((ext_vector_type(8)));
typedef float  f32x4  __attribute__((ext_vector_type(4)));

#define NBLK 1344          // 5376 windows / 4 per block
// pair offsets (1 pair = 2 bf16) of pre-swizzled weights inside d_ws
#define WP_QKV  0
#define WP_PROJ 55296
#define WP_MLP1 73728
#define WP_MLP2 147456
#define WP_TOT  221184
// bf16 element offsets
#define WF_QKV  0
#define WF_PROJ 110592
#define WF_MLP1 147456
#define WF_MLP2 294912

// ---------------- merged weight pre-swizzle: W[K][N] f32 -> B-fragment bf16 ----------------
// frag(nt,kt): dst[((nt*Kt + kt)*64 + lane)*8 + j] = W[kt*32 + (lane>>4)*8 + j][nt*16 + (lane&15)]
__global__ void preproc_all(const float* __restrict__ qkv_w, const float* __restrict__ proj_w,
                            const float* __restrict__ mlp_w1, const float* __restrict__ mlp_w2,
                            bf16_t* __restrict__ dst) {
    int p = blockIdx.x * 256 + threadIdx.x;
    if (p >= WP_TOT) return;
    const float* W; int N, Kt; int q = p;
    if (p < WP_PROJ)      { W = qkv_w;  N = 576; Kt = 6;  }
    else if (p < WP_MLP1) { W = proj_w; N = 192; Kt = 6;  q -= WP_PROJ; }
    else if (p < WP_MLP2) { W = mlp_w1; N = 768; Kt = 6;  q -= WP_MLP1; }
    else                  { W = mlp_w2; N = 192; Kt = 24; q -= WP_MLP2; }
    int j    = (q & 3) * 2;
    int lane = (q >> 2) & 63;
    int kt   = (q >> 8) % Kt;
    int nt   = (q >> 8) / Kt;
    int k = kt * 32 + (lane >> 4) * 8 + j;
    int n = nt * 16 + (lane & 15);
    union { bf16_t h[2]; unsigned u; } pk;
    pk.h[0] = (bf16_t)W[k * N + n];
    pk.h[1] = (bf16_t)W[(k + 1) * N + n];
    *(unsigned*)(dst + p * 2) = pk.u;
}

// ---------------- main fused kernel ----------------
// R8 anchor (341us: 4-window/768-thread/12-wave) + ONE change: dense bias table.
// The attention S-init did a double-indirect gather per thread (32x rel_index +
// 32x bias_table scattered dwords, up to ~16 cache lines per 16-lane group) on
// the critical path between Q-scatter and S-MFMA. (bias,rel_index) depend only
// on (h,n,m) -> identical for all blocks: materialize sBias[6][24][24] bf16 in
// LDS once per block (~4.5 gathers/thread at start, overlapped with LN1) and
// read it conflict-benign in the win loop.
// Occupancy note: capped at 3 waves/SIMD (MLP reg peak ~170 unified) = one
// 768-thread block/CU; LDS is free up to 160KB. 160128 B total <= 163840 OK.
//
// LDS arena (152064 B):
//  aA    [0,38400)       bf16 [96][200]  LN1 out / QKV A (4 windows compact)
//  wavebufs 38400+wv*9344 (x12 = 112128 B, attention phase only, dead after):
//      Qb  [24][40] @0     per-window Q (Pb aliases)
//      Kb2 [48][40] @1920  K both windows of pair g
//      Vt  [32][56] @5760  V^T both windows (+8 pad cols zeroed)
//  aO    [0,38400)       attn out / proj A (aliases aA)
//  aH2   [0,38400)       LN2 out / MLP A (aliases aO)
//  xw2b  [38400,76800)   bf16 [96][200]  residual1 copy (aliases dead wavebufs)
//  aHid  [76800,152064)  bf16 [96][392]  half-width gelu buffer, 784-B rows
// + sBias 6912 B + statics 1152 B -> 160128 B total.
// NOTE: erff gelu (fast_gelu regressed R5); kt loops NOT pragma-unrolled (R2).
__global__ __launch_bounds__(768, 3)
void pangu_main(const float* __restrict__ x,
                const float* __restrict__ ln1_g, const float* __restrict__ ln1_b,
                const float* __restrict__ qkv_b,
                const float* __restrict__ bias_table,
                const float* __restrict__ proj_b,
                const float* __restrict__ ln2_g, const float* __restrict__ ln2_b,
                const float* __restrict__ mlp_b1, const float* __restrict__ mlp_b2,
                const int* __restrict__ rel_index,
                const bf16_t* __restrict__ wf,
                float* __restrict__ out)
{
    __shared__ __align__(16) unsigned char arena[152064];
    __shared__ int   sRowOff[96];
    __shared__ float sMu[96], sRs[96];
    __shared__ bf16_t sBias[3456];    // [6 heads][24 n][24 m]

    unsigned char* aAb   = arena;
    unsigned char* aOb   = arena;                 // alias aA (post-QKV barrier)
    unsigned char* aH2b  = arena;                 // alias aO (dead)
    unsigned char* xw2b  = arena + 38400;
    unsigned char* aHidb = arena + 76800;         // [96][392] bf16, 784-B rows
    bf16_t* aO   = (bf16_t*)aOb;
    bf16_t* aHid = (bf16_t*)aHidb;
    bf16_t* xw2h = (bf16_t*)xw2b;

    const int t    = threadIdx.x;
    const int lane = t & 63;
    const int wv   = t >> 6;          // 0..11
    const int h    = wv >> 1;         // head 0..5
    const int g    = wv & 1;          // window-pair 0..1
    const int quad = lane >> 4;
    const int l15  = lane & 15;
    const int q4   = quad * 4;

    // ---- row offsets of the 96 tokens (4 windows) ----
    if (t < 96) {
        int win = t / 24, tok = t % 24;
        int W = blockIdx.x * 4 + win;
        int id_ = W % 7;  int r1 = W / 7;
        int iw_ = r1 % 16; int r2 = r1 / 16;
        int ih_ = r2 % 24; int b  = r2 / 24;
        int i = tok / 12, j = (tok % 12) / 2, k = tok % 2;
        sRowOff[t] = (((b * 48 + ih_ * 2 + i) * 96 + iw_ * 6 + j) * 14 + id_ * 2 + k) * 192;
    }
    // ---- dense bias table fill (block-invariant; overlaps with LN1 latency) ----
    for (int p = t; p < 3456; p += 768) {
        int hh  = p / 576;
        int rem = p % 576;            // n*24 + m
        sBias[p] = (bf16_t)bias_table[rel_index[rem] * 6 + hh];
    }
    __syncthreads();

    // ---- LN1 entirely in registers: 8 threads/row, 96 rows ----
    {
        int r96 = t >> 3, l = t & 7;
        const float* xr = x + sRowOff[r96];
        float4 v[6];
        #pragma unroll
        for (int s = 0; s < 6; ++s) v[s] = *(const float4*)(xr + l * 4 + s * 32);
        float sm = 0.f, s2 = 0.f;
        #pragma unroll
        for (int s = 0; s < 6; ++s) {
            sm += v[s].x + v[s].y + v[s].z + v[s].w;
            s2 += v[s].x * v[s].x + v[s].y * v[s].y + v[s].z * v[s].z + v[s].w * v[s].w;
        }
        sm += __shfl_xor(sm, 1); s2 += __shfl_xor(s2, 1);
        sm += __shfl_xor(sm, 2); s2 += __shfl_xor(s2, 2);
        sm += __shfl_xor(sm, 4); s2 += __shfl_xor(s2, 4);
        float mu = sm * (1.f / 192.f);
        float var = s2 * (1.f / 192.f) - mu * mu;
        float rs = rsqrtf(var + 1e-5f);
        #pragma unroll
        for (int s = 0; s < 6; ++s) {
            int c = l * 4 + s * 32;
            union { bf16_t h4[4]; uint2 u; } pk;
            pk.h4[0] = (bf16_t)((v[s].x - mu) * rs * ln1_g[c]     + ln1_b[c]);
            pk.h4[1] = (bf16_t)((v[s].y - mu) * rs * ln1_g[c + 1] + ln1_b[c + 1]);
            pk.h4[2] = (bf16_t)((v[s].z - mu) * rs * ln1_g[c + 2] + ln1_b[c + 2]);
            pk.h4[3] = (bf16_t)((v[s].w - mu) * rs * ln1_g[c + 3] + ln1_b[c + 3]);
            *(uint2*)(aAb + r96 * 400 + c * 2) = pk.u;
        }
    }
    __syncthreads();

    // ================= QKV GEMM (2 passes) + attention =================
    // wave (h,g): M tiles {3g,3g+1,3g+2} (rows 48g..48g+47 = windows 2g,2g+1)
    {
        unsigned char* wb = arena + 38400 + wv * 9344;
        bf16_t* Qb  = (bf16_t*)wb;                 // [24][40] per-win; Pb aliases
        bf16_t* Kb2 = (bf16_t*)(wb + 1920);        // [48][40] both windows of pair
        bf16_t* Vt  = (bf16_t*)(wb + 5760);        // [32][56] both windows (+pad)
        bf16_t* Pb  = (bf16_t*)wb;

        // ---- pass 1: K,V ntiles (4 per head), acc[3][4] ----
        {
            f32x4 acc[3][4];
            const int ntg[4] = {12+2*h, 13+2*h, 24+2*h, 25+2*h};
            float bq[4];
            #pragma unroll
            for (int n = 0; n < 4; ++n) bq[n] = qkv_b[ntg[n] * 16 + l15];
            #pragma unroll
            for (int m = 0; m < 3; ++m)
                #pragma unroll
                for (int n = 0; n < 4; ++n)
                    acc[m][n] = (f32x4){bq[n], bq[n], bq[n], bq[n]};
            for (int kt = 0; kt < 6; ++kt) {
                bf16x8 af[3];
                #pragma unroll
                for (int m = 0; m < 3; ++m)
                    af[m] = *(const bf16x8*)(aAb + (l15 + (3*g + m) * 16) * 400 + kt * 64 + quad * 16);
                #pragma unroll
                for (int n = 0; n < 4; ++n) {
                    bf16x8 bfr = *(const bf16x8*)(wf + WF_QKV + ((ntg[n] * 6 + kt) * 64 + lane) * 8);
                    #pragma unroll
                    for (int m = 0; m < 3; ++m)
                        acc[m][n] = __builtin_amdgcn_mfma_f32_16x16x32_bf16(af[m], bfr, acc[m][n], 0, 0, 0);
                }
            }
            // scatter K and V^T (pair-local rows 0..47); wave-private, no barrier
            #pragma unroll
            for (int m = 0; m < 3; ++m)
                #pragma unroll
                for (int i = 0; i < 4; ++i) {
                    int row = m * 16 + q4 + i;   // 0..47 pair-local token
                    #pragma unroll
                    for (int nt = 0; nt < 2; ++nt) {
                        int d = nt * 16 + l15;
                        Kb2[row * 40 + d] = (bf16_t)(acc[m][nt][i]);
                        Vt[d * 56 + row]  = (bf16_t)(acc[m][2+nt][i]);
                    }
                }
            // zero Vt pad cols 48..55
            {
                int d = lane >> 1, half = lane & 1;
                *(uint2*)((unsigned char*)Vt + d * 112 + 96 + half * 8) = make_uint2(0u, 0u);
            }
        }

        // ---- pass 2: Q ntiles (2 per head), qacc[3][2] live through win loop ----
        f32x4 qacc[3][2];
        {
            const int ntg[2] = {2*h, 2*h+1};
            float bq[2];
            #pragma unroll
            for (int n = 0; n < 2; ++n) bq[n] = qkv_b[ntg[n] * 16 + l15];
            #pragma unroll
            for (int m = 0; m < 3; ++m)
                #pragma unroll
                for (int n = 0; n < 2; ++n)
                    qacc[m][n] = (f32x4){bq[n], bq[n], bq[n], bq[n]};
            for (int kt = 0; kt < 6; ++kt) {
                bf16x8 af[3];
                #pragma unroll
                for (int m = 0; m < 3; ++m)
                    af[m] = *(const bf16x8*)(aAb + (l15 + (3*g + m) * 16) * 400 + kt * 64 + quad * 16);
                #pragma unroll
                for (int n = 0; n < 2; ++n) {
                    bf16x8 bfr = *(const bf16x8*)(wf + WF_QKV + ((ntg[n] * 6 + kt) * 64 + lane) * 8);
                    #pragma unroll
                    for (int m = 0; m < 3; ++m)
                        qacc[m][n] = __builtin_amdgcn_mfma_f32_16x16x32_bf16(af[m], bfr, qacc[m][n], 0, 0, 0);
                }
            }
        }
        __syncthreads();   // all waves done reading aA; aO (alias) written below

        const float scale = 0.1767766952966369f;  // 1/sqrt(32)
        #pragma unroll
        for (int w01 = 0; w01 < 2; ++w01) {        // local window within pair g
            // scatter Q (scaled) for this window from qacc
            #pragma unroll
            for (int m = 0; m < 3; ++m)
                #pragma unroll
                for (int i = 0; i < 4; ++i) {
                    int tok = m * 16 + q4 + i - w01 * 24;
                    if (tok >= 0 && tok < 24) {
                        #pragma unroll
                        for (int nt = 0; nt < 2; ++nt)
                            Qb[tok * 40 + nt * 16 + l15] = (bf16_t)(qacc[m][nt][i] * scale);
                    }
                }
            // S = Qs.K^T + bias  (bias from dense LDS table as C-init)
            f32x4 sacc[2][2];
            #pragma unroll
            for (int mt = 0; mt < 2; ++mt)
                #pragma unroll
                for (int nt = 0; nt < 2; ++nt)
                    #pragma unroll
                    for (int i = 0; i < 4; ++i) {
                        int n = mt * 16 + q4 + i; if (n > 23) n = 23;
                        int m = nt * 16 + l15;    if (m > 23) m = 23;
                        sacc[mt][nt][i] = (float)sBias[(h * 24 + n) * 24 + m];
                    }
            #pragma unroll
            for (int nt = 0; nt < 2; ++nt) {
                bf16x8 kf = *(const bf16x8*)((unsigned char*)Kb2 + (w01 * 24 + l15 + nt * 16) * 80 + quad * 16);
                #pragma unroll
                for (int mt = 0; mt < 2; ++mt) {
                    bf16x8 qf = *(const bf16x8*)((unsigned char*)Qb + (l15 + mt * 16) * 80 + quad * 16);
                    sacc[mt][nt] = __builtin_amdgcn_mfma_f32_16x16x32_bf16(qf, kf, sacc[mt][nt], 0, 0, 0);
                }
            }
            // in-register softmax over cols 0..23
            #pragma unroll
            for (int mt = 0; mt < 2; ++mt)
                #pragma unroll
                for (int i = 0; i < 4; ++i) {
                    float s0 = sacc[mt][0][i];
                    float s1m = (l15 < 8) ? sacc[mt][1][i] : -1e30f;
                    float mx = fmaxf(s0, s1m);
                    mx = fmaxf(mx, __shfl_xor(mx, 1));
                    mx = fmaxf(mx, __shfl_xor(mx, 2));
                    mx = fmaxf(mx, __shfl_xor(mx, 4));
                    mx = fmaxf(mx, __shfl_xor(mx, 8));
                    float e0 = __expf(s0 - mx);
                    float e1 = (l15 < 8) ? __expf(sacc[mt][1][i] - mx) : 0.f;
                    float sum = e0 + e1;
                    sum += __shfl_xor(sum, 1);
                    sum += __shfl_xor(sum, 2);
                    sum += __shfl_xor(sum, 4);
                    sum += __shfl_xor(sum, 8);
                    float inv = 1.f / sum;
                    sacc[mt][0][i] = e0 * inv;
                    sacc[mt][1][i] = e1 * inv;   // 0 for cols 24..31
                }
            // P -> LDS (A-operand layout; aliases Qb, Q dead for this window)
            #pragma unroll
            for (int mt = 0; mt < 2; ++mt)
                #pragma unroll
                for (int i = 0; i < 4; ++i) {
                    int r = mt * 16 + q4 + i;
                    if (r < 24) {
                        Pb[r * 40 + l15]      = (bf16_t)sacc[mt][0][i];
                        Pb[r * 40 + 16 + l15] = (bf16_t)sacc[mt][1][i];
                    }
                }
            // O = P.V
            f32x4 oacc[2][2];
            #pragma unroll
            for (int mt = 0; mt < 2; ++mt)
                #pragma unroll
                for (int nt = 0; nt < 2; ++nt)
                    oacc[mt][nt] = (f32x4){0.f, 0.f, 0.f, 0.f};
            #pragma unroll
            for (int nt = 0; nt < 2; ++nt) {
                bf16x8 vf = *(const bf16x8*)((unsigned char*)Vt + (l15 + nt * 16) * 112 + w01 * 48 + quad * 16);
                #pragma unroll
                for (int mt = 0; mt < 2; ++mt) {
                    bf16x8 pf = *(const bf16x8*)((unsigned char*)Pb + (l15 + mt * 16) * 80 + quad * 16);
                    oacc[mt][nt] = __builtin_amdgcn_mfma_f32_16x16x32_bf16(pf, vf, oacc[mt][nt], 0, 0, 0);
                }
            }
            // O -> aO (96-row compact, proj A layout)
            #pragma unroll
            for (int mt = 0; mt < 2; ++mt)
                #pragma unroll
                for (int i = 0; i < 4; ++i) {
                    int tok = mt * 16 + q4 + i;
                    if (tok < 24) {
                        int r = 48 * g + w01 * 24 + tok;
                        #pragma unroll
                        for (int nt = 0; nt < 2; ++nt)
                            aO[r * 200 + h * 32 + nt * 16 + l15] = (bf16_t)oacc[mt][nt][i];
                    }
                }
        } // w01
    }
    __syncthreads();

    // ================= proj GEMM (wave: 3 m-tiles of pair g, ntiles {2h,2h+1}) =================
    float rxw[3][2][4];   // f32 residual carried in registers to the final store
    {
        f32x4 pacc[3][2];
        #pragma unroll
        for (int m = 0; m < 3; ++m)
            #pragma unroll
            for (int n = 0; n < 2; ++n) pacc[m][n] = (f32x4){0.f, 0.f, 0.f, 0.f};
        for (int kt = 0; kt < 6; ++kt) {
            bf16x8 af[3];
            #pragma unroll
            for (int m = 0; m < 3; ++m)
                af[m] = *(const bf16x8*)(aOb + (l15 + (3*g + m) * 16) * 400 + kt * 64 + quad * 16);
            #pragma unroll
            for (int n = 0; n < 2; ++n) {
                int NT = 2 * h + n;
                bf16x8 bfr = *(const bf16x8*)(wf + WF_PROJ + ((NT * 6 + kt) * 64 + lane) * 8);
                #pragma unroll
                for (int m = 0; m < 3; ++m)
                    pacc[m][n] = __builtin_amdgcn_mfma_f32_16x16x32_bf16(af[m], bfr, pacc[m][n], 0, 0, 0);
            }
        }
        // epilogue straight to xw2 (region disjoint from aO -> no barrier needed)
        #pragma unroll
        for (int n = 0; n < 2; ++n) {
            int c = (2 * h + n) * 16 + l15;
            float pb = proj_b[c];
            #pragma unroll
            for (int m = 0; m < 3; ++m)
                #pragma unroll
                for (int i = 0; i < 4; ++i) {
                    int r = (3*g + m) * 16 + q4 + i;
                    float val = x[sRowOff[r] + c] + pb + pacc[m][n][i];
                    rxw[m][n][i] = val;
                    xw2h[r * 200 + c] = (bf16_t)val;
                }
        }
    }
    __syncthreads();

    // ---- LN2 stats from bf16 xw2 copy (8 threads/row, 96 rows) ----
    {
        int r = t >> 3, l = t & 7;
        float sm = 0.f, s2 = 0.f;
        #pragma unroll
        for (int s = 0; s < 6; ++s) {
            union { bf16_t h4[4]; uint2 u; } pk;
            pk.u = *(const uint2*)(xw2b + r * 400 + l * 8 + s * 64);
            #pragma unroll
            for (int z = 0; z < 4; ++z) { float v = (float)pk.h4[z]; sm += v; s2 += v * v; }
        }
        sm += __shfl_xor(sm, 1); s2 += __shfl_xor(s2, 1);
        sm += __shfl_xor(sm, 2); s2 += __shfl_xor(s2, 2);
        sm += __shfl_xor(sm, 4); s2 += __shfl_xor(s2, 4);
        if (l == 0) {
            float mu = sm * (1.f / 192.f);
            float var = s2 * (1.f / 192.f) - mu * mu;
            sMu[r] = mu; sRs[r] = rsqrtf(var + 1e-5f);
        }
    }
    __syncthreads();
    // ---- LN2 normalize -> aH2 (all proj K-loop reads of aO finished at stats barrier) ----
    for (int p = t; p < 9216; p += 768) {
        int r = p / 96, c2 = p % 96, c = c2 * 2;
        float mu = sMu[r], rs = sRs[r];
        union { bf16_t h2[2]; unsigned u; } in, pk;
        in.u = *(const unsigned*)(xw2b + r * 400 + c2 * 4);
        pk.h2[0] = (bf16_t)(((float)in.h2[0] - mu) * rs * ln2_g[c]     + ln2_b[c]);
        pk.h2[1] = (bf16_t)(((float)in.h2[1] - mu) * rs * ln2_g[c + 1] + ln2_b[c + 1]);
        *(unsigned*)(aH2b + r * 400 + c2 * 4) = pk.u;
    }
    __syncthreads();

    // ================= MLP: 2 chunks of 384 hidden cols =================
    // chunk c: MLP1 wave (h,g): ntiles {c*24+4h..+3} x its 3 m-tiles -> a1[3][4]
    //          -> gelu -> aHid[96][392] (784-B rows, conflict-free) -> barrier
    //          MLP2: 12 k-tiles of chunk, ntiles {2h,2h+1} x 3 m -> acc2[3][2]
    f32x4 acc2[3][2];
    #pragma unroll
    for (int m = 0; m < 3; ++m)
        #pragma unroll
        for (int n = 0; n < 2; ++n) {
            float b2 = mlp_b2[(2 * h + n) * 16 + l15];
            acc2[m][n] = (f32x4){b2, b2, b2, b2};
        }
    for (int ch = 0; ch < 2; ++ch) {
        f32x4 a1[3][4];
        #pragma unroll
        for (int m = 0; m < 3; ++m)
            #pragma unroll
            for (int n = 0; n < 4; ++n) {
                float b1 = mlp_b1[(ch * 24 + 4 * h + n) * 16 + l15];
                a1[m][n] = (f32x4){b1, b1, b1, b1};
            }
        for (int kt = 0; kt < 6; ++kt) {
            bf16x8 af[3];
            #pragma unroll
            for (int m = 0; m < 3; ++m)
                af[m] = *(const bf16x8*)(aH2b + (l15 + (3*g + m) * 16) * 400 + kt * 64 + quad * 16);
            #pragma unroll
            for (int n = 0; n < 4; ++n) {
                int NT = ch * 24 + 4 * h + n;
                bf16x8 bfr = *(const bf16x8*)(wf + WF_MLP1 + ((NT * 6 + kt) * 64 + lane) * 8);
                #pragma unroll
                for (int m = 0; m < 3; ++m)
                    a1[m][n] = __builtin_amdgcn_mfma_f32_16x16x32_bf16(af[m], bfr, a1[m][n], 0, 0, 0);
            }
        }
        // exact gelu -> aHid chunk-local cols (4h+n)*16+l15, rows of pair g
        #pragma unroll
        for (int n = 0; n < 4; ++n) {
            int c = (4 * h + n) * 16 + l15;
            #pragma unroll
            for (int m = 0; m < 3; ++m)
                #pragma unroll
                for (int i = 0; i < 4; ++i) {
                    int r = (3*g + m) * 16 + q4 + i;
                    float v = a1[m][n][i];
                    float gl = 0.5f * v * (1.f + erff(v * 0.70710678118654752f));
                    aHid[r * 392 + c] = (bf16_t)gl;
                }
        }
        __syncthreads();
        // MLP2 partial over this chunk's 12 k-tiles
        for (int ktl = 0; ktl < 12; ++ktl) {
            bf16x8 af[3];
            #pragma unroll
            for (int m = 0; m < 3; ++m)
                af[m] = *(const bf16x8*)(aHidb + (l15 + (3*g + m) * 16) * 784 + ktl * 64 + quad * 16);
            #pragma unroll
            for (int n = 0; n < 2; ++n) {
                int NT = 2 * h + n;
                int ktg = ch * 12 + ktl;
                bf16x8 bfr = *(const bf16x8*)(wf + WF_MLP2 + ((NT * 24 + ktg) * 64 + lane) * 8);
                #pragma unroll
                for (int m = 0; m < 3; ++m)
                    acc2[m][n] = __builtin_amdgcn_mfma_f32_16x16x32_bf16(af[m], bfr, acc2[m][n], 0, 0, 0);
            }
        }
        if (ch == 0) __syncthreads();   // aHid reread safety before chunk 1 overwrite
    }

    // ---- final: out = xw2(regs) + mlp ----
    #pragma unroll
    for (int n = 0; n < 2; ++n) {
        int c = (2 * h + n) * 16 + l15;
        #pragma unroll
        for (int m = 0; m < 3; ++m)
            #pragma unroll
            for (int i = 0; i < 4; ++i) {
                int r = (3*g + m) * 16 + q4 + i;
                out[sRowOff[r] + c] = rxw[m][n][i] + acc2[m][n][i];
            }
    }
}

extern "C" void kernel_launch(void* const* d_in, const int* in_sizes, int n_in,
                              void* d_out, int out_size, void* d_ws, size_t ws_size,
                              hipStream_t stream) {
    const float* x          = (const float*)d_in[0];
    const float* ln1_g      = (const float*)d_in[1];
    const float* ln1_b      = (const float*)d_in[2];
    const float* qkv_w      = (const float*)d_in[3];
    const float* qkv_b      = (const float*)d_in[4];
    const float* bias_table = (const float*)d_in[5];
    const float* proj_w     = (const float*)d_in[6];
    const float* proj_b     = (const float*)d_in[7];
    const float* ln2_g      = (const float*)d_in[8];
    const float* ln2_b      = (const float*)d_in[9];
    const float* mlp_w1     = (const float*)d_in[10];
    const float* mlp_b1     = (const float*)d_in[11];
    const float* mlp_w2     = (const float*)d_in[12];
    const float* mlp_b2     = (const float*)d_in[13];
    const int*   rel_index  = (const int*)d_in[14];
    float* out = (float*)d_out;
    bf16_t* wsb = (bf16_t*)d_ws;

    preproc_all<<<(WP_TOT + 255) / 256, 256, 0, stream>>>(qkv_w, proj_w, mlp_w1, mlp_w2, wsb);

    pangu_main<<<NBLK, 768, 0, stream>>>(
        x, ln1_g, ln1_b, qkv_b, bias_table, proj_b, ln2_g, ln2_b,
        mlp_b1, mlp_b2, rel_index, wsb, out);
}